// Round 2
// baseline (270.173 us; speedup 1.0000x reference)
//
#include <hip/hip_runtime.h>
#include <hip/hip_bf16.h>
#include <hip/hip_cooperative_groups.h>

namespace cg = cooperative_groups;

typedef __attribute__((ext_vector_type(8))) short bf16x8;
typedef __attribute__((ext_vector_type(4))) float f32x4;

#define D_DIM 256   // input feature dim
#define H_DIM 128   // hidden dim per branch

// RNE float->bf16 (bit pattern)
__device__ inline ushort f2bf(float f) {
    union { float f; unsigned u; } a; a.f = f;
    unsigned r = a.u + 0x7fffu + ((a.u >> 16) & 1u);
    return (ushort)(r >> 16);
}

// K0: init rowsum to 1e-10; build Wt[256][256] bf16 where row hcat = sel*128+h, col k.
__global__ void k0_init(const float* __restrict__ W_nb, const float* __restrict__ W_self,
                        ushort* __restrict__ Wt, float* __restrict__ rowsum, int N) {
    int i = blockIdx.x * 256 + threadIdx.x;
    if (i < 2 * H_DIM * D_DIM) {
        int sel = i >> 15;        // 0: nb, 1: self (32768 elems each)
        int r   = i & 32767;
        int k   = r >> 7;         // 0..255 (coalesced reads along h)
        int h   = r & 127;        // 0..127
        const float* W = sel ? W_self : W_nb;
        Wt[(sel * H_DIM + h) * D_DIM + k] = f2bf(W[k * H_DIM + h]);
    }
    if (i < N) rowsum[i] = 1e-10f;
}

// K1: per-node fused GEMM:
//   Y = relu(X @ [W_nb | W_self] + [b_nb | b_self])   (rows = nodes, 256 cols)
//   g_nb[n]   = sum_h Y[n][h]     * W_att[h]
//   g_self[n] = sum_h Y[n][128+h] * W_att[128+h]
// BM=64 nodes/block, 2 waves x 32 rows x 256 cols, BK=64, K=256.
__global__ __launch_bounds__(128, 2) void k1_gemm(
    const float* __restrict__ x, const ushort* __restrict__ Wt,
    const float* __restrict__ b_nb, const float* __restrict__ b_self,
    const float* __restrict__ W_att,
    float* __restrict__ g_nb, float* __restrict__ g_self, int N)
{
    __shared__ __align__(16) ushort A_lds[64][72];    // [node][k], +8 pad
    __shared__ __align__(16) ushort B_lds[256][72];   // [hcat][k], +8 pad

    const int t    = threadIdx.x;
    const int lane = t & 63;
    const int wave = t >> 6;       // 0..1
    const int li   = lane & 15;
    const int grp  = lane >> 4;
    const int block_row = blockIdx.x * 64;

    f32x4 acc[2][16];
    #pragma unroll
    for (int mi = 0; mi < 2; mi++)
        #pragma unroll
        for (int ni = 0; ni < 16; ni++) acc[mi][ni] = f32x4{0.f, 0.f, 0.f, 0.f};

    const int arow  = t >> 1;      // 0..63
    const int ahalf = t & 1;       // which 32-wide half of the 64-wide K slice
    const int garow = block_row + arow;
    const bool avalid = garow < N;

    for (int kt = 0; kt < 4; kt++) {
        const int k0 = kt * 64;
        __syncthreads();
        // ---- stage A: 64x64 f32 -> bf16 (reg-staged, converted) ----
        {
            ushort4 o[8];
            if (avalid) {
                const float4* src = reinterpret_cast<const float4*>(x + (size_t)garow * D_DIM + k0 + ahalf * 32);
                #pragma unroll
                for (int j = 0; j < 8; j++) {
                    float4 v = src[j];
                    o[j].x = f2bf(v.x); o[j].y = f2bf(v.y); o[j].z = f2bf(v.z); o[j].w = f2bf(v.w);
                }
            } else {
                #pragma unroll
                for (int j = 0; j < 8; j++) { o[j].x = 0; o[j].y = 0; o[j].z = 0; o[j].w = 0; }
            }
            #pragma unroll
            for (int j = 0; j < 8; j++)
                *reinterpret_cast<ushort4*>(&A_lds[arow][ahalf * 32 + j * 4]) = o[j];
        }
        // ---- stage B: 256 rows x 64 bf16 (already bf16 in Wt) ----
        #pragma unroll
        for (int rr = 0; rr < 2; rr++) {
            int hrow = t + rr * 128;
            const uint4* src = reinterpret_cast<const uint4*>(Wt + hrow * D_DIM + k0);
            uint4* dst = reinterpret_cast<uint4*>(&B_lds[hrow][0]);
            #pragma unroll
            for (int j = 0; j < 8; j++) dst[j] = src[j];
        }
        __syncthreads();

        // ---- MFMA: 2 (mi) x 16 (ni) x 2 (kk) per K-iter ----
        bf16x8 afrag[2][2];
        #pragma unroll
        for (int mi = 0; mi < 2; mi++)
            #pragma unroll
            for (int kk = 0; kk < 2; kk++)
                afrag[mi][kk] = *reinterpret_cast<const bf16x8*>(
                    &A_lds[wave * 32 + mi * 16 + li][kk * 32 + grp * 8]);
        #pragma unroll
        for (int ni = 0; ni < 16; ni++) {
            bf16x8 b0 = *reinterpret_cast<const bf16x8*>(&B_lds[ni * 16 + li][grp * 8]);
            bf16x8 b1 = *reinterpret_cast<const bf16x8*>(&B_lds[ni * 16 + li][32 + grp * 8]);
            #pragma unroll
            for (int mi = 0; mi < 2; mi++) {
                acc[mi][ni] = __builtin_amdgcn_mfma_f32_16x16x32_bf16(afrag[mi][0], b0, acc[mi][ni], 0, 0, 0);
                acc[mi][ni] = __builtin_amdgcn_mfma_f32_16x16x32_bf16(afrag[mi][1], b1, acc[mi][ni], 0, 0, 0);
            }
        }
    }

    // ---- epilogue: bias + relu + W_att weighted row-sum ----
    float pn[2][4], ps[2][4];
    #pragma unroll
    for (int mi = 0; mi < 2; mi++)
        #pragma unroll
        for (int r = 0; r < 4; r++) { pn[mi][r] = 0.f; ps[mi][r] = 0.f; }

    #pragma unroll
    for (int ni = 0; ni < 16; ni++) {
        int hcat = ni * 16 + li;            // 0..255; ni<8 -> nb branch, ni>=8 -> self
        int hh   = hcat & 127;
        float bias = (ni < 8) ? b_nb[hh] : b_self[hh];
        float aw   = W_att[hcat];
        #pragma unroll
        for (int mi = 0; mi < 2; mi++)
            #pragma unroll
            for (int r = 0; r < 4; r++) {
                float y = acc[mi][ni][r] + bias;
                y = y > 0.f ? y : 0.f;
                if (ni < 8) pn[mi][r] += y * aw; else ps[mi][r] += y * aw;
            }
    }

    // reduce across the 16 lanes (li) of each group; C/D rows = grp*4 + r
    #pragma unroll
    for (int mi = 0; mi < 2; mi++)
        #pragma unroll
        for (int r = 0; r < 4; r++) {
            float a_ = pn[mi][r], s_ = ps[mi][r];
            #pragma unroll
            for (int m = 1; m < 16; m <<= 1) {
                a_ += __shfl_xor(a_, m);
                s_ += __shfl_xor(s_, m);
            }
            if (li == 0) {
                int n = block_row + wave * 32 + mi * 16 + grp * 4 + r;
                if (n < N) { g_nb[n] = a_; g_self[n] = s_; }
            }
        }
}

// K2 (cooperative, fused edge pass):
//   phase A: gate, mask, mv in regs; atomicAdd rowsum
//   grid.sync()
//   phase B: out[e] = mv * rsqrt(rs[row]) * rsqrt(rs[col])
// gate simplification: z = log(u/(1-u)) + la ; sigmoid(z) = u / (u + (1-u)*exp(-la))
#define K2_BLOCKS 1024
#define K2_ITERS  4
__global__ __launch_bounds__(256, 4) void k2_fused(
    const int* __restrict__ row, const int* __restrict__ col,
    const float* __restrict__ values, const float* __restrict__ noise,
    const float* __restrict__ g_nb, const float* __restrict__ g_self,
    const float* __restrict__ b_att,
    float* __restrict__ out, float* __restrict__ rowsum, int E)
{
    const int base   = blockIdx.x * 256 + threadIdx.x;
    const int stride = K2_BLOCKS * 256;
    const float ba = b_att[0];

    int   rr[K2_ITERS], cc[K2_ITERS];
    float mv[K2_ITERS];

    #pragma unroll
    for (int it = 0; it < K2_ITERS; it++) {
        int e = base + it * stride;
        rr[it] = 0; cc[it] = 0; mv[it] = 0.f;
        if (e < E) {
            int   r = row[e], c = col[e];
            float v = values[e];
            float u = noise[e] + 1e-7f;
            float la = g_nb[r] + g_self[c] + ba;
            float gate = u / (u + (1.f - u) * __expf(-la));
            float mask = fminf(fmaxf(gate * 1.6f - 0.5f, 0.f), 1.f);
            float m = v * mask;
            rr[it] = r; cc[it] = c; mv[it] = m;
            atomicAdd(&rowsum[r], m);
        }
    }

    __threadfence();
    cg::this_grid().sync();

    #pragma unroll
    for (int it = 0; it < K2_ITERS; it++) {
        int e = base + it * stride;
        if (e < E) {
            out[e] = mv[it] * rsqrtf(rowsum[rr[it]]) * rsqrtf(rowsum[cc[it]]);
        }
    }
}

extern "C" void kernel_launch(void* const* d_in, const int* in_sizes, int n_in,
                              void* d_out, int out_size, void* d_ws, size_t ws_size,
                              hipStream_t stream) {
    const float* x      = (const float*)d_in[0];
    const float* W_nb   = (const float*)d_in[1];
    const float* b_nb   = (const float*)d_in[2];
    const float* W_self = (const float*)d_in[3];
    const float* b_self = (const float*)d_in[4];
    const float* W_att  = (const float*)d_in[5];
    const float* b_att  = (const float*)d_in[6];
    const float* values = (const float*)d_in[7];
    const float* noise  = (const float*)d_in[8];
    const int*   row    = (const int*)d_in[9];
    const int*   col    = (const int*)d_in[10];

    const int N = in_sizes[0] / D_DIM;
    const int E = in_sizes[7];
    float* out = (float*)d_out;

    char* ws = (char*)d_ws;
    ushort* Wt     = (ushort*)ws;                       // 2*128*256*2 = 131072 B
    float*  g_nb   = (float*)(ws + 131072);             // N floats
    float*  g_self = g_nb + N;                          // N floats
    float*  rowsum = g_self + N;                        // N floats

    int init_elems = 2 * H_DIM * D_DIM;                 // 65536
    int init_n = init_elems > N ? init_elems : N;
    k0_init<<<(init_n + 255) / 256, 256, 0, stream>>>(W_nb, W_self, Wt, rowsum, N);

    k1_gemm<<<(N + 63) / 64, 128, 0, stream>>>(x, Wt, b_nb, b_self, W_att, g_nb, g_self, N);

    void* args[] = { (void*)&row, (void*)&col, (void*)&values, (void*)&noise,
                     (void*)&g_nb, (void*)&g_self, (void*)&b_att,
                     (void*)&out, (void*)&rowsum, (void*)&E };
    hipLaunchCooperativeKernel((void*)k2_fused, dim3(K2_BLOCKS), dim3(256), args, 0, stream);
}

// Round 3
// 98.909 us; speedup vs baseline: 2.7315x; 2.7315x over previous
//
#include <hip/hip_runtime.h>
#include <hip/hip_bf16.h>

typedef __attribute__((ext_vector_type(8))) short bf16x8;
typedef __attribute__((ext_vector_type(4))) float f32x4;

#define D_DIM 256   // input feature dim
#define H_DIM 128   // hidden dim per branch

// RNE float->bf16 (bit pattern)
__device__ inline ushort f2bf(float f) {
    union { float f; unsigned u; } a; a.f = f;
    unsigned r = a.u + 0x7fffu + ((a.u >> 16) & 1u);
    return (ushort)(r >> 16);
}

// K0: init rowsum to 1e-10; build Wt[256][256] bf16 where row hcat = sel*128+h, col k.
__global__ void k0_init(const float* __restrict__ W_nb, const float* __restrict__ W_self,
                        ushort* __restrict__ Wt, float* __restrict__ rowsum, int N) {
    int i = blockIdx.x * 256 + threadIdx.x;
    if (i < 2 * H_DIM * D_DIM) {
        int sel = i >> 15;        // 0: nb, 1: self (32768 elems each)
        int r   = i & 32767;
        int k   = r >> 7;         // 0..255 (coalesced reads along h)
        int h   = r & 127;        // 0..127
        const float* W = sel ? W_self : W_nb;
        Wt[(sel * H_DIM + h) * D_DIM + k] = f2bf(W[k * H_DIM + h]);
    }
    if (i < N) rowsum[i] = 1e-10f;
}

// K1: per-node fused GEMM:
//   Y = relu(X @ [W_nb | W_self] + [b_nb | b_self])   (rows = nodes, 256 cols)
//   g_nb[n]   = sum_h Y[n][h]     * W_att[h]
//   g_self[n] = sum_h Y[n][128+h] * W_att[128+h]
// BM=64 nodes/block, 2 waves x 32 rows x 256 cols, BK=64, K=256.
__global__ __launch_bounds__(128, 2) void k1_gemm(
    const float* __restrict__ x, const ushort* __restrict__ Wt,
    const float* __restrict__ b_nb, const float* __restrict__ b_self,
    const float* __restrict__ W_att,
    float* __restrict__ g_nb, float* __restrict__ g_self, int N)
{
    __shared__ __align__(16) ushort A_lds[64][72];    // [node][k], +8 pad
    __shared__ __align__(16) ushort B_lds[256][72];   // [hcat][k], +8 pad

    const int t    = threadIdx.x;
    const int lane = t & 63;
    const int wave = t >> 6;       // 0..1
    const int li   = lane & 15;
    const int grp  = lane >> 4;
    const int block_row = blockIdx.x * 64;

    f32x4 acc[2][16];
    #pragma unroll
    for (int mi = 0; mi < 2; mi++)
        #pragma unroll
        for (int ni = 0; ni < 16; ni++) acc[mi][ni] = f32x4{0.f, 0.f, 0.f, 0.f};

    const int arow  = t >> 1;      // 0..63
    const int ahalf = t & 1;       // which 32-wide half of the 64-wide K slice
    const int garow = block_row + arow;
    const bool avalid = garow < N;

    for (int kt = 0; kt < 4; kt++) {
        const int k0 = kt * 64;
        __syncthreads();
        // ---- stage A: 64x64 f32 -> bf16 (reg-staged, converted) ----
        {
            ushort4 o[8];
            if (avalid) {
                const float4* src = reinterpret_cast<const float4*>(x + (size_t)garow * D_DIM + k0 + ahalf * 32);
                #pragma unroll
                for (int j = 0; j < 8; j++) {
                    float4 v = src[j];
                    o[j].x = f2bf(v.x); o[j].y = f2bf(v.y); o[j].z = f2bf(v.z); o[j].w = f2bf(v.w);
                }
            } else {
                #pragma unroll
                for (int j = 0; j < 8; j++) { o[j].x = 0; o[j].y = 0; o[j].z = 0; o[j].w = 0; }
            }
            #pragma unroll
            for (int j = 0; j < 8; j++)
                *reinterpret_cast<ushort4*>(&A_lds[arow][ahalf * 32 + j * 4]) = o[j];
        }
        // ---- stage B: 256 rows x 64 bf16 (already bf16 in Wt) ----
        #pragma unroll
        for (int rr = 0; rr < 2; rr++) {
            int hrow = t + rr * 128;
            const uint4* src = reinterpret_cast<const uint4*>(Wt + hrow * D_DIM + k0);
            uint4* dst = reinterpret_cast<uint4*>(&B_lds[hrow][0]);
            #pragma unroll
            for (int j = 0; j < 8; j++) dst[j] = src[j];
        }
        __syncthreads();

        // ---- MFMA: 2 (mi) x 16 (ni) x 2 (kk) per K-iter ----
        bf16x8 afrag[2][2];
        #pragma unroll
        for (int mi = 0; mi < 2; mi++)
            #pragma unroll
            for (int kk = 0; kk < 2; kk++)
                afrag[mi][kk] = *reinterpret_cast<const bf16x8*>(
                    &A_lds[wave * 32 + mi * 16 + li][kk * 32 + grp * 8]);
        #pragma unroll
        for (int ni = 0; ni < 16; ni++) {
            bf16x8 b0 = *reinterpret_cast<const bf16x8*>(&B_lds[ni * 16 + li][grp * 8]);
            bf16x8 b1 = *reinterpret_cast<const bf16x8*>(&B_lds[ni * 16 + li][32 + grp * 8]);
            #pragma unroll
            for (int mi = 0; mi < 2; mi++) {
                acc[mi][ni] = __builtin_amdgcn_mfma_f32_16x16x32_bf16(afrag[mi][0], b0, acc[mi][ni], 0, 0, 0);
                acc[mi][ni] = __builtin_amdgcn_mfma_f32_16x16x32_bf16(afrag[mi][1], b1, acc[mi][ni], 0, 0, 0);
            }
        }
    }

    // ---- epilogue: bias + relu + W_att weighted row-sum ----
    float pn[2][4], ps[2][4];
    #pragma unroll
    for (int mi = 0; mi < 2; mi++)
        #pragma unroll
        for (int r = 0; r < 4; r++) { pn[mi][r] = 0.f; ps[mi][r] = 0.f; }

    #pragma unroll
    for (int ni = 0; ni < 16; ni++) {
        int hcat = ni * 16 + li;            // 0..255; ni<8 -> nb branch, ni>=8 -> self
        int hh   = hcat & 127;
        float bias = (ni < 8) ? b_nb[hh] : b_self[hh];
        float aw   = W_att[hcat];
        #pragma unroll
        for (int mi = 0; mi < 2; mi++)
            #pragma unroll
            for (int r = 0; r < 4; r++) {
                float y = acc[mi][ni][r] + bias;
                y = y > 0.f ? y : 0.f;
                if (ni < 8) pn[mi][r] += y * aw; else ps[mi][r] += y * aw;
            }
    }

    // reduce across the 16 lanes (li) of each group; C/D rows = grp*4 + r
    #pragma unroll
    for (int mi = 0; mi < 2; mi++)
        #pragma unroll
        for (int r = 0; r < 4; r++) {
            float a_ = pn[mi][r], s_ = ps[mi][r];
            #pragma unroll
            for (int m = 1; m < 16; m <<= 1) {
                a_ += __shfl_xor(a_, m);
                s_ += __shfl_xor(s_, m);
            }
            if (li == 0) {
                int n = block_row + wave * 32 + mi * 16 + grp * 4 + r;
                if (n < N) { g_nb[n] = a_; g_self[n] = s_; }
            }
        }
}

// K2: edge pass 1 — 1 edge/thread. gate, mask, mv -> out; atomic rowsum.
// sigmoid(log(u/(1-u)) + la) = u / (u + (1-u)*exp(-la))
__global__ __launch_bounds__(256) void k2_edge1(
    const int* __restrict__ row, const int* __restrict__ col,
    const float* __restrict__ values, const float* __restrict__ noise,
    const float* __restrict__ g_nb, const float* __restrict__ g_self,
    const float* __restrict__ b_att,
    float* __restrict__ mv_out, float* __restrict__ rowsum, int E)
{
    int e = blockIdx.x * 256 + threadIdx.x;
    if (e >= E) return;
    int   r = row[e], c = col[e];
    float v = values[e];
    float u = noise[e] + 1e-7f;
    float la = g_nb[r] + g_self[c] + b_att[0];
    float gate = u / (u + (1.f - u) * __expf(-la));
    float mask = fminf(fmaxf(gate * 1.6f - 0.5f, 0.f), 1.f);
    float m = v * mask;
    mv_out[e] = m;
    atomicAdd(&rowsum[r], m);
}

// K3: edge pass 2 — 1 edge/thread, symmetric degree normalization in place.
__global__ __launch_bounds__(256) void k3_edge2(
    const int* __restrict__ row, const int* __restrict__ col,
    float* __restrict__ out, const float* __restrict__ rowsum, int E)
{
    int e = blockIdx.x * 256 + threadIdx.x;
    if (e >= E) return;
    out[e] = out[e] * rsqrtf(rowsum[row[e]]) * rsqrtf(rowsum[col[e]]);
}

extern "C" void kernel_launch(void* const* d_in, const int* in_sizes, int n_in,
                              void* d_out, int out_size, void* d_ws, size_t ws_size,
                              hipStream_t stream) {
    const float* x      = (const float*)d_in[0];
    const float* W_nb   = (const float*)d_in[1];
    const float* b_nb   = (const float*)d_in[2];
    const float* W_self = (const float*)d_in[3];
    const float* b_self = (const float*)d_in[4];
    const float* W_att  = (const float*)d_in[5];
    const float* b_att  = (const float*)d_in[6];
    const float* values = (const float*)d_in[7];
    const float* noise  = (const float*)d_in[8];
    const int*   row    = (const int*)d_in[9];
    const int*   col    = (const int*)d_in[10];

    const int N = in_sizes[0] / D_DIM;
    const int E = in_sizes[7];
    float* out = (float*)d_out;

    char* ws = (char*)d_ws;
    ushort* Wt     = (ushort*)ws;                       // 2*128*256*2 = 131072 B
    float*  g_nb   = (float*)(ws + 131072);             // N floats
    float*  g_self = g_nb + N;                          // N floats
    float*  rowsum = g_self + N;                        // N floats

    int init_elems = 2 * H_DIM * D_DIM;                 // 65536
    int init_n = init_elems > N ? init_elems : N;
    k0_init<<<(init_n + 255) / 256, 256, 0, stream>>>(W_nb, W_self, Wt, rowsum, N);

    k1_gemm<<<(N + 63) / 64, 128, 0, stream>>>(x, Wt, b_nb, b_self, W_att, g_nb, g_self, N);

    int eb = (E + 255) / 256;
    k2_edge1<<<eb, 256, 0, stream>>>(row, col, values, noise, g_nb, g_self, b_att, out, rowsum, E);
    k3_edge2<<<eb, 256, 0, stream>>>(row, col, out, rowsum, E);
}